// Round 4
// baseline (138.450 us; speedup 1.0000x reference)
//
#include <hip/hip_runtime.h>
#include <hip/hip_bf16.h>

typedef unsigned short ushort_t;
typedef __attribute__((ext_vector_type(8))) short s16x8;
typedef __attribute__((ext_vector_type(4))) float f32x4;

#define NB 8192
#define ND 128
#define BMR 64              // rows per block (shared by all 4 waves)
#define CHUNK 1024          // cols per block; wave w owns cols w*32 + step*128
#define NCHUNK (NB/CHUNK)   // 8
#define NSTEP 8             // 1024 / (4 waves * 32 cols)
#define EPS 1e-8f
#define MARGIN 1.0f

// ---- kernel 1: f32 -> bf16 + row squared-norms ----
__global__ void prep_kernel(const float* __restrict__ E,
                            ushort_t* __restrict__ Ebf,
                            float* __restrict__ sqA) {
    const int tid  = threadIdx.x;
    const int lane = tid & 63;
    const int row  = blockIdx.x * 4 + (tid >> 6);

    const float2 v = reinterpret_cast<const float2*>(E + (size_t)row * ND)[lane];
    __hip_bfloat16 b0 = __float2bfloat16(v.x);
    __hip_bfloat16 b1 = __float2bfloat16(v.y);
    ushort_t pk[2] = { *reinterpret_cast<ushort_t*>(&b0), *reinterpret_cast<ushort_t*>(&b1) };
    *reinterpret_cast<uint*>(&Ebf[(size_t)row * ND + lane * 2]) = *reinterpret_cast<uint*>(pk);

    float ss = v.x * v.x + v.y * v.y;
    #pragma unroll
    for (int off = 32; off; off >>= 1) ss += __shfl_down(ss, off, 64);
    if (lane == 0) sqA[row] = ss;
}

// ---- kernel 2: barrier-free Gram fold; B frags straight from L2 ----
__global__ __launch_bounds__(256, 2) void triplet_gemm(
        const ushort_t* __restrict__ Ebf,
        const int* __restrict__ labels,
        float* __restrict__ pvPart,      // [NCHUNK][NB]: min dot over positives
        float* __restrict__ nvPart) {    // [NCHUNK][NB]: max dot over negatives
    __shared__ float pvRed[4][BMR];
    __shared__ float nvRed[4][BMR];

    const int tid = threadIdx.x, lane = tid & 63, w = tid >> 6;
    const int fr = lane & 15, fg = lane >> 4;
    const int rowBase = blockIdx.x * BMR;
    const int colBase = blockIdx.y * CHUNK + w * 32;

    // hoist A fragments for 64 rows x K=128 (16 x global b128 gathers, L2-hit)
    s16x8 a[4][4];
    #pragma unroll
    for (int ks = 0; ks < 4; ++ks)
        #pragma unroll
        for (int mi = 0; mi < 4; ++mi)
            a[ks][mi] = *reinterpret_cast<const s16x8*>(
                Ebf + (size_t)(rowBase + mi * 16 + fr) * ND + ks * 32 + fg * 8);

    int labR[4][4];
    #pragma unroll
    for (int mi = 0; mi < 4; ++mi)
        #pragma unroll
        for (int reg = 0; reg < 4; ++reg)
            labR[mi][reg] = labels[rowBase + mi * 16 + fg * 4 + reg];

    int labC[NSTEP][2];
    #pragma unroll
    for (int s = 0; s < NSTEP; ++s)
        #pragma unroll
        for (int ni = 0; ni < 2; ++ni)
            labC[s][ni] = labels[colBase + s * 128 + ni * 16 + fr];

    const float PINF = __builtin_inff(), NINF = -__builtin_inff();
    f32x4 pv[4], nv[4];
    #pragma unroll
    for (int mi = 0; mi < 4; ++mi) {
        pv[mi] = f32x4{PINF, PINF, PINF, PINF};
        nv[mi] = f32x4{NINF, NINF, NINF, NINF};
    }

    s16x8 bA[8], bB[8];   // [ks*2+ni], double-buffered across steps

    auto loadB = [&](s16x8* b, int s) {
        const ushort_t* base = Ebf + (size_t)(colBase + s * 128) * ND;
        #pragma unroll
        for (int ks = 0; ks < 4; ++ks)
            #pragma unroll
            for (int ni = 0; ni < 2; ++ni)
                b[ks * 2 + ni] = *reinterpret_cast<const s16x8*>(
                    base + (size_t)(ni * 16 + fr) * ND + ks * 32 + fg * 8);
    };

    auto step = [&](const s16x8* b, int s) {
        const f32x4 zf = {0.f, 0.f, 0.f, 0.f};
        f32x4 acc[4][2];
        #pragma unroll
        for (int mi = 0; mi < 4; ++mi)
            #pragma unroll
            for (int ni = 0; ni < 2; ++ni)
                acc[mi][ni] = __builtin_amdgcn_mfma_f32_16x16x32_bf16(a[0][mi], b[ni], zf, 0, 0, 0);
        #pragma unroll
        for (int ks = 1; ks < 4; ++ks)
            #pragma unroll
            for (int mi = 0; mi < 4; ++mi)
                #pragma unroll
                for (int ni = 0; ni < 2; ++ni)
                    acc[mi][ni] = __builtin_amdgcn_mfma_f32_16x16x32_bf16(
                        a[ks][mi], b[ks * 2 + ni], acc[mi][ni], 0, 0, 0);
        // fold: pos -> min dot, neg -> max dot (d monotone in -dot; |e|^2 == 1)
        #pragma unroll
        for (int mi = 0; mi < 4; ++mi)
            #pragma unroll
            for (int ni = 0; ni < 2; ++ni)
                #pragma unroll
                for (int reg = 0; reg < 4; ++reg) {
                    float d = acc[mi][ni][reg];
                    bool eq = (labR[mi][reg] == labC[s][ni]);
                    pv[mi][reg] = fminf(pv[mi][reg], eq ? d : PINF);
                    nv[mi][reg] = fmaxf(nv[mi][reg], eq ? NINF : d);
                }
    };

    loadB(bA, 0);
    #pragma unroll
    for (int tt = 0; tt < NSTEP; tt += 2) {
        if (tt + 1 < NSTEP) loadB(bB, tt + 1);
        step(bA, tt);
        if (tt + 2 < NSTEP) loadB(bA, tt + 2);
        step(bB, tt + 1);
    }

    // cross-lane then cross-wave reduce; one coalesced partial store per row
    #pragma unroll
    for (int mi = 0; mi < 4; ++mi)
        #pragma unroll
        for (int reg = 0; reg < 4; ++reg) {
            float p = pv[mi][reg], n = nv[mi][reg];
            #pragma unroll
            for (int off = 1; off < 16; off <<= 1) {
                p = fminf(p, __shfl_xor(p, off, 64));
                n = fmaxf(n, __shfl_xor(n, off, 64));
            }
            if (fr == 0) {
                pvRed[w][mi * 16 + fg * 4 + reg] = p;
                nvRed[w][mi * 16 + fg * 4 + reg] = n;
            }
        }
    __syncthreads();
    if (tid < BMR) {
        float p = fminf(fminf(pvRed[0][tid], pvRed[1][tid]),
                        fminf(pvRed[2][tid], pvRed[3][tid]));
        float n = fmaxf(fmaxf(nvRed[0][tid], nvRed[1][tid]),
                        fmaxf(nvRed[2][tid], nvRed[3][tid]));
        pvPart[(size_t)blockIdx.y * NB + rowBase + tid] = p;
        nvPart[(size_t)blockIdx.y * NB + rowBase + tid] = n;
    }
}

// ---- kernel 3a: per-row loss, deterministic block partials ----
__global__ void finalize_partial(const float* __restrict__ sqA,
                                 const float* __restrict__ pvPart,
                                 const float* __restrict__ nvPart,
                                 float* __restrict__ fpart) {
    __shared__ float sl[4], sc[4];
    const int tid = threadIdx.x, lane = tid & 63, w = tid >> 6;
    const int i = blockIdx.x * 256 + tid;
    const float PINF = __builtin_inff(), NINF = -__builtin_inff();

    float pMin = PINF, nMax = NINF;
    #pragma unroll
    for (int c = 0; c < NCHUNK; ++c) {
        pMin = fminf(pMin, pvPart[(size_t)c * NB + i]);
        nMax = fmaxf(nMax, nvPart[(size_t)c * NB + i]);
    }
    bool valid = (pMin < PINF) && (nMax > NINF);
    float sq = sqA[i];
    float pd = sqrtf(fmaxf(sq + 1.0f - 2.0f * pMin, 0.f) + EPS);
    float nd = sqrtf(fmaxf(sq + 1.0f - 2.0f * nMax, 0.f) + EPS);
    float l  = fmaxf(pd - nd + MARGIN, 0.f);
    float lv = valid ? l : 0.f;
    float cv = valid ? 1.f : 0.f;
    #pragma unroll
    for (int off = 32; off; off >>= 1) {
        lv += __shfl_down(lv, off, 64);
        cv += __shfl_down(cv, off, 64);
    }
    if (lane == 0) { sl[w] = lv; sc[w] = cv; }
    __syncthreads();
    if (tid == 0) {
        fpart[blockIdx.x * 2]     = sl[0] + sl[1] + sl[2] + sl[3];
        fpart[blockIdx.x * 2 + 1] = sc[0] + sc[1] + sc[2] + sc[3];
    }
}

// ---- kernel 3b: final deterministic sum + write ----
__global__ void finalize_write(const float* __restrict__ fpart, float* __restrict__ out) {
    if (threadIdx.x == 0) {
        float L = 0.f, C = 0.f;
        #pragma unroll
        for (int k = 0; k < NB / 256; ++k) { L += fpart[2 * k]; C += fpart[2 * k + 1]; }
        out[0] = (C > 0.f) ? (L / C) : 0.f;
        out[1] = C;
    }
}

extern "C" void kernel_launch(void* const* d_in, const int* in_sizes, int n_in,
                              void* d_out, int out_size, void* d_ws, size_t ws_size,
                              hipStream_t stream) {
    const float* E      = (const float*)d_in[0];
    const int*   labels = (const int*)d_in[1];
    float*       out    = (float*)d_out;

    char* ws = (char*)d_ws;
    ushort_t* Ebf    = (ushort_t*)ws;                                  // 2 MiB
    float*    sqA    = (float*)(ws + (size_t)NB * ND * 2);             // 32 KiB
    float*    pvPart = (float*)(ws + (size_t)NB * ND * 2 + NB * 4);    // 256 KiB
    float*    nvPart = (float*)(ws + (size_t)NB * ND * 2 + NB * 4 + (size_t)NCHUNK * NB * 4);
    float*    fpart  = (float*)(ws + (size_t)NB * ND * 2 + NB * 4 + 2 * (size_t)NCHUNK * NB * 4);

    prep_kernel<<<NB / 4, 256, 0, stream>>>(E, Ebf, sqA);

    dim3 grid(NB / BMR, NCHUNK);
    triplet_gemm<<<grid, 256, 0, stream>>>(Ebf, labels, pvPart, nvPart);

    finalize_partial<<<NB / 256, 256, 0, stream>>>(sqA, pvPart, nvPart, fpart);
    finalize_write<<<1, 64, 0, stream>>>(fpart, out);
}

// Round 5
// 41.587 us; speedup vs baseline: 3.3291x; 3.3291x over previous
//
#include <hip/hip_runtime.h>
#include <hip/hip_bf16.h>

typedef unsigned short ushort_t;
typedef __attribute__((ext_vector_type(8))) short s16x8;
typedef __attribute__((ext_vector_type(4))) float f32x4;

#define NB 8192
#define ND 128
#define BMR 128             // rows per block (4 waves x 32)
#define TCOLS 64            // cols per B tile
#define CHUNK 1024          // cols per block
#define NT (CHUNK/TCOLS)    // 16
#define NCHUNK (NB/CHUNK)   // 8
#define EPS 1e-8f
#define MARGIN 1.0f

typedef const __attribute__((address_space(1))) void* gptr_t;
typedef __attribute__((address_space(3))) void* lptr_t;
__device__ __forceinline__ void gll16(const void* g, void* l) {
    __builtin_amdgcn_global_load_lds((gptr_t)g, (lptr_t)l, 16, 0, 0);
}

// stage ROWSx128 bf16 tile global->LDS, 16B/lane, source-swizzled:
// LDS[r][s] = G[r][s ^ (r&7)]  (s = 16B slot, 16 slots/row)
template <int ITERS>
__device__ __forceinline__ void stage_rows(const ushort_t* __restrict__ g,
                                           ushort_t* l, int tid, int w) {
    #pragma unroll
    for (int it = 0; it < ITERS; ++it) {
        const int c = it * 256 + tid;          // 16B chunk id
        const int r = c >> 4, s = c & 15;
        const int ss = s ^ (r & 7);
        gll16(g + r * ND + ss * 8, l + (it * 256 + w * 64) * 8);
    }
}

// ---- kernel 1: f32 -> bf16 + row squared-norms ----
__global__ void prep_kernel(const float* __restrict__ E,
                            ushort_t* __restrict__ Ebf,
                            float* __restrict__ sqA) {
    const int tid  = threadIdx.x;
    const int lane = tid & 63;
    const int row  = blockIdx.x * 4 + (tid >> 6);

    const float2 v = reinterpret_cast<const float2*>(E + (size_t)row * ND)[lane];
    __hip_bfloat16 b0 = __float2bfloat16(v.x);
    __hip_bfloat16 b1 = __float2bfloat16(v.y);
    ushort_t pk[2] = { *reinterpret_cast<ushort_t*>(&b0), *reinterpret_cast<ushort_t*>(&b1) };
    *reinterpret_cast<uint*>(&Ebf[(size_t)row * ND + lane * 2]) = *reinterpret_cast<uint*>(pk);

    float ss = v.x * v.x + v.y * v.y;
    #pragma unroll
    for (int off = 32; off; off >>= 1) ss += __shfl_down(ss, off, 64);
    if (lane == 0) sqA[row] = ss;
}

// ---- kernel 2: 128-row stripe x 1024-col chunk; wave owns 32 rows ----
__global__ __launch_bounds__(256, 1) void triplet_gemm(
        const ushort_t* __restrict__ Ebf,
        const int* __restrict__ labels,
        float* __restrict__ pvPart,      // [NCHUNK][NB]: min dot over positives
        float* __restrict__ nvPart) {    // [NCHUNK][NB]: max dot over negatives
    __shared__ __align__(16) ushort_t As[BMR * ND];        // 32 KB
    __shared__ __align__(16) ushort_t Bb[2][TCOLS * ND];   // 32 KB

    const int tid = threadIdx.x, lane = tid & 63, w = tid >> 6;
    const int fr = lane & 15, fg = lane >> 4;
    const int rowBase = blockIdx.x * BMR;
    const int chunkBase = blockIdx.y * CHUNK;
    const int wrow = w * 32;               // wave's rows within the stripe

    // prologue: stage A stripe + B tile0
    stage_rows<8>(Ebf + (size_t)rowBase * ND, As, tid, w);
    stage_rows<4>(Ebf + (size_t)chunkBase * ND, &Bb[0][0], tid, w);

    int labR[2][4];
    #pragma unroll
    for (int mi = 0; mi < 2; ++mi)
        #pragma unroll
        for (int reg = 0; reg < 4; ++reg)
            labR[mi][reg] = labels[rowBase + wrow + mi * 16 + fg * 4 + reg];

    int swByte[4];
    #pragma unroll
    for (int ks = 0; ks < 4; ++ks) swByte[ks] = ((ks * 4 + fg) ^ (fr & 7)) * 16;

    asm volatile("s_waitcnt vmcnt(0)" ::: "memory");
    __builtin_amdgcn_s_barrier();
    __builtin_amdgcn_sched_barrier(0);

    // hoist this wave's A fragments: 32 rows x K=128 = 8 frags = 32 VGPR
    s16x8 a[4][2];
    {
        const char* ap = (const char*)As;
        #pragma unroll
        for (int ks = 0; ks < 4; ++ks)
            #pragma unroll
            for (int mi = 0; mi < 2; ++mi)
                a[ks][mi] = *reinterpret_cast<const s16x8*>(
                    ap + (wrow + mi * 16 + fr) * 256 + swByte[ks]);
    }

    const float PINF = __builtin_inff(), NINF = -__builtin_inff();
    f32x4 pv[2], nv[2];
    #pragma unroll
    for (int mi = 0; mi < 2; ++mi) {
        pv[mi] = f32x4{PINF, PINF, PINF, PINF};
        nv[mi] = f32x4{NINF, NINF, NINF, NINF};
    }

    auto tile_step = [&](int t, const ushort_t* cur, ushort_t* nxt) {
        if (t + 1 < NT)
            stage_rows<4>(Ebf + (size_t)(chunkBase + (t + 1) * TCOLS) * ND, nxt, tid, w);

        const char* cp = (const char*)cur;
        const f32x4 zf = {0.f, 0.f, 0.f, 0.f};
        #pragma unroll
        for (int ni = 0; ni < 4; ++ni) {
            const int labC = labels[chunkBase + t * TCOLS + ni * 16 + fr];
            s16x8 b[4];
            #pragma unroll
            for (int ks = 0; ks < 4; ++ks)
                b[ks] = *reinterpret_cast<const s16x8*>(
                    cp + (ni * 16 + fr) * 256 + swByte[ks]);
            f32x4 acc0 = __builtin_amdgcn_mfma_f32_16x16x32_bf16(a[0][0], b[0], zf, 0, 0, 0);
            f32x4 acc1 = __builtin_amdgcn_mfma_f32_16x16x32_bf16(a[0][1], b[0], zf, 0, 0, 0);
            #pragma unroll
            for (int ks = 1; ks < 4; ++ks) {
                acc0 = __builtin_amdgcn_mfma_f32_16x16x32_bf16(a[ks][0], b[ks], acc0, 0, 0, 0);
                acc1 = __builtin_amdgcn_mfma_f32_16x16x32_bf16(a[ks][1], b[ks], acc1, 0, 0, 0);
            }
            #pragma unroll
            for (int reg = 0; reg < 4; ++reg) {
                bool eq0 = (labR[0][reg] == labC);
                bool eq1 = (labR[1][reg] == labC);
                pv[0][reg] = fminf(pv[0][reg], eq0 ? acc0[reg] : PINF);
                nv[0][reg] = fmaxf(nv[0][reg], eq0 ? NINF : acc0[reg]);
                pv[1][reg] = fminf(pv[1][reg], eq1 ? acc1[reg] : PINF);
                nv[1][reg] = fmaxf(nv[1][reg], eq1 ? NINF : acc1[reg]);
            }
        }
        asm volatile("s_waitcnt vmcnt(0) lgkmcnt(0)" ::: "memory");
        __builtin_amdgcn_sched_barrier(0);
        __builtin_amdgcn_s_barrier();
        __builtin_amdgcn_sched_barrier(0);
    };

    #pragma unroll 1
    for (int tt = 0; tt < NT; tt += 2) {
        tile_step(tt,     &Bb[0][0], &Bb[1][0]);
        tile_step(tt + 1, &Bb[1][0], &Bb[0][0]);
    }

    // epilogue: 16-lane reduce; fr==0 lanes store this wave's 32 rows directly
    #pragma unroll
    for (int mi = 0; mi < 2; ++mi)
        #pragma unroll
        for (int reg = 0; reg < 4; ++reg) {
            float p = pv[mi][reg], n = nv[mi][reg];
            #pragma unroll
            for (int off = 1; off < 16; off <<= 1) {
                p = fminf(p, __shfl_xor(p, off, 64));
                n = fmaxf(n, __shfl_xor(n, off, 64));
            }
            if (fr == 0) {
                const int grow = rowBase + wrow + mi * 16 + fg * 4 + reg;
                pvPart[(size_t)blockIdx.y * NB + grow] = p;
                nvPart[(size_t)blockIdx.y * NB + grow] = n;
            }
        }
}

// ---- kernel 3a: per-row loss, deterministic block partials ----
__global__ void finalize_partial(const float* __restrict__ sqA,
                                 const float* __restrict__ pvPart,
                                 const float* __restrict__ nvPart,
                                 float* __restrict__ fpart) {
    __shared__ float sl[4], sc[4];
    const int tid = threadIdx.x, lane = tid & 63, w = tid >> 6;
    const int i = blockIdx.x * 256 + tid;
    const float PINF = __builtin_inff(), NINF = -__builtin_inff();

    float pMin = PINF, nMax = NINF;
    #pragma unroll
    for (int c = 0; c < NCHUNK; ++c) {
        pMin = fminf(pMin, pvPart[(size_t)c * NB + i]);
        nMax = fmaxf(nMax, nvPart[(size_t)c * NB + i]);
    }
    bool valid = (pMin < PINF) && (nMax > NINF);
    float sq = sqA[i];
    float pd = sqrtf(fmaxf(sq + 1.0f - 2.0f * pMin, 0.f) + EPS);
    float nd = sqrtf(fmaxf(sq + 1.0f - 2.0f * nMax, 0.f) + EPS);
    float l  = fmaxf(pd - nd + MARGIN, 0.f);
    float lv = valid ? l : 0.f;
    float cv = valid ? 1.f : 0.f;
    #pragma unroll
    for (int off = 32; off; off >>= 1) {
        lv += __shfl_down(lv, off, 64);
        cv += __shfl_down(cv, off, 64);
    }
    if (lane == 0) { sl[w] = lv; sc[w] = cv; }
    __syncthreads();
    if (tid == 0) {
        fpart[blockIdx.x * 2]     = sl[0] + sl[1] + sl[2] + sl[3];
        fpart[blockIdx.x * 2 + 1] = sc[0] + sc[1] + sc[2] + sc[3];
    }
}

// ---- kernel 3b: final deterministic sum + write ----
__global__ void finalize_write(const float* __restrict__ fpart, float* __restrict__ out) {
    if (threadIdx.x == 0) {
        float L = 0.f, C = 0.f;
        #pragma unroll
        for (int k = 0; k < NB / 256; ++k) { L += fpart[2 * k]; C += fpart[2 * k + 1]; }
        out[0] = (C > 0.f) ? (L / C) : 0.f;
        out[1] = C;
    }
}

extern "C" void kernel_launch(void* const* d_in, const int* in_sizes, int n_in,
                              void* d_out, int out_size, void* d_ws, size_t ws_size,
                              hipStream_t stream) {
    const float* E      = (const float*)d_in[0];
    const int*   labels = (const int*)d_in[1];
    float*       out    = (float*)d_out;

    char* ws = (char*)d_ws;
    ushort_t* Ebf    = (ushort_t*)ws;                                  // 2 MiB
    float*    sqA    = (float*)(ws + (size_t)NB * ND * 2);             // 32 KiB
    float*    pvPart = (float*)(ws + (size_t)NB * ND * 2 + NB * 4);    // 256 KiB
    float*    nvPart = (float*)(ws + (size_t)NB * ND * 2 + NB * 4 + (size_t)NCHUNK * NB * 4);
    float*    fpart  = (float*)(ws + (size_t)NB * ND * 2 + NB * 4 + 2 * (size_t)NCHUNK * NB * 4);

    prep_kernel<<<NB / 4, 256, 0, stream>>>(E, Ebf, sqA);

    dim3 grid(NB / BMR, NCHUNK);
    triplet_gemm<<<grid, 256, 0, stream>>>(Ebf, labels, pvPart, nvPart);

    finalize_partial<<<NB / 256, 256, 0, stream>>>(sqA, pvPart, nvPart, fpart);
    finalize_write<<<1, 64, 0, stream>>>(fpart, out);
}

// Round 6
// 40.016 us; speedup vs baseline: 3.4599x; 1.0393x over previous
//
#include <hip/hip_runtime.h>
#include <hip/hip_bf16.h>

typedef unsigned short ushort_t;
typedef __attribute__((ext_vector_type(8))) short s16x8;
typedef __attribute__((ext_vector_type(4))) float f32x4;

#define NB 8192
#define ND 128
#define KE 192              // 128 emb + 64 one-hot label cols
#define ROWB (KE*2)         // 384 bytes per row
#define WROWS 64            // rows per wave (mi=4)
#define BMR 256             // rows per block (4 waves)
#define TCOLS 64            // cols per B tile
#define CHUNK 512           // cols per block
#define NTILE (CHUNK/TCOLS) // 8
#define NCHUNK (NB/CHUNK)   // 16
#define EPS 1e-8f
#define MARGIN 1.0f

typedef const __attribute__((address_space(1))) void* gptr_t;
typedef __attribute__((address_space(3))) void* lptr_t;
__device__ __forceinline__ void gll16(const void* g, void* l) {
    __builtin_amdgcn_global_load_lds((gptr_t)g, (lptr_t)l, 16, 0, 0);
}

// ---- kernel 1: f32 -> bf16 + one-hot(+1.0) label cols + row squared-norms ----
__global__ void prep_kernel(const float* __restrict__ E,
                            const int* __restrict__ labels,
                            ushort_t* __restrict__ Eb,
                            float* __restrict__ sqA) {
    const int tid  = threadIdx.x;
    const int lane = tid & 63;
    const int row  = blockIdx.x * 4 + (tid >> 6);

    const float2 v = reinterpret_cast<const float2*>(E + (size_t)row * ND)[lane];
    __hip_bfloat16 b0 = __float2bfloat16(v.x);
    __hip_bfloat16 b1 = __float2bfloat16(v.y);
    uint pk = (uint)*reinterpret_cast<ushort_t*>(&b0)
            | ((uint)*reinterpret_cast<ushort_t*>(&b1) << 16);
    uint* rowp = reinterpret_cast<uint*>(Eb + (size_t)row * KE);
    rowp[lane] = pk;                       // emb cols 0..127

    if (lane < 32) {                       // one-hot cols 128..191, value 1.0 bf16
        const int lab = labels[row];
        const int c0 = lane * 2, c1 = lane * 2 + 1;
        uint e = (uint)((lab == c0) ? 0x3F80u : 0u)
               | (((lab == c1) ? 0x3F80u : 0u) << 16);
        rowp[64 + lane] = e;
    }

    float ss = v.x * v.x + v.y * v.y;
    #pragma unroll
    for (int off = 32; off; off >>= 1) ss += __shfl_down(ss, off, 64);
    if (lane == 0) sqA[row] = ss;
}

// ---- kernel 2: 256-row stripe x 512-col chunk; u = dot - 8*eq via MFMA ----
__global__ __launch_bounds__(256, 1) void triplet_gemm(
        const ushort_t* __restrict__ Eb,
        const int* __restrict__ labels,
        float* __restrict__ pvPart,      // [NCHUNK][NB]: min u (hardest positive)
        float* __restrict__ nvPart) {    // [NCHUNK][NB]: max u (hardest negative)
    __shared__ __align__(16) ushort_t Bb[3][TCOLS * KE];   // 3 x 24 KB

    const int tid = threadIdx.x, lane = tid & 63, w = tid >> 6;
    const int fr = lane & 15, fg = lane >> 4;
    const int rowBase = blockIdx.x * BMR;
    const int chunkBase = blockIdx.y * CHUNK;
    const int wrow = rowBase + w * WROWS;

    // staging offsets: chunk c = it*256+tid -> row r=c/24, slot s=c%24, src swizzled
    int srcOff[6];
    #pragma unroll
    for (int it = 0; it < 6; ++it) {
        const int c = it * 256 + tid;
        const int r = c / 24, s = c - r * 24;
        srcOff[it] = r * ROWB + ((s ^ (r & 7)) << 4);
    }
    auto stage = [&](int bufi, int t) {
        const char* g = (const char*)Eb + (size_t)(chunkBase + t * TCOLS) * ROWB;
        char* l = (char*)&Bb[0][0] + bufi * (TCOLS * KE * 2);
        #pragma unroll
        for (int it = 0; it < 6; ++it)
            gll16(g + srcOff[it], l + (it * 256 + w * 64) * 16);
    };

    // swizzled read offsets: slot (ks*4+fg) ^ (fr&7)  (row&7 == fr&7 since 16%8==0)
    int swb[6];
    #pragma unroll
    for (int ks = 0; ks < 6; ++ks) swb[ks] = (((ks * 4 + fg) ^ (fr & 7)) << 4);

    // prologue: row labels, A emb frags (global/L2), first two stages
    int labv[4];
    #pragma unroll
    for (int mi = 0; mi < 4; ++mi) labv[mi] = labels[wrow + mi * 16 + fr];

    s16x8 a[6][4];
    #pragma unroll
    for (int ks = 0; ks < 4; ++ks)
        #pragma unroll
        for (int mi = 0; mi < 4; ++mi)
            a[ks][mi] = *reinterpret_cast<const s16x8*>(
                (const char*)Eb + (size_t)(wrow + mi * 16 + fr) * ROWB + ks * 64 + fg * 16);

    stage(0, 0);
    stage(1, 1);
    asm volatile("s_waitcnt vmcnt(6)" ::: "memory");   // labs+a+stage0 done; stage1 in flight
    __builtin_amdgcn_sched_barrier(0);
    __builtin_amdgcn_s_barrier();
    __builtin_amdgcn_sched_barrier(0);

    // synthesize A one-hot frags: value -8.0 bf16 at col == label
    #pragma unroll
    for (int ks = 4; ks < 6; ++ks)
        #pragma unroll
        for (int mi = 0; mi < 4; ++mi) {
            s16x8 t{};
            #pragma unroll
            for (int j = 0; j < 8; ++j) {
                const int c = (ks - 4) * 32 + fg * 8 + j;
                t[j] = (labv[mi] == c) ? (short)0xC100 : (short)0;
            }
            a[ks][mi] = t;
        }

    const float PINF = __builtin_inff(), NINF = -__builtin_inff();
    f32x4 pv[4], nv[4];
    #pragma unroll
    for (int mi = 0; mi < 4; ++mi) {
        pv[mi] = f32x4{PINF, PINF, PINF, PINF};
        nv[mi] = f32x4{NINF, NINF, NINF, NINF};
    }
    const f32x4 zf = {0.f, 0.f, 0.f, 0.f};

    #pragma unroll 1
    for (int p = 0; p < NTILE; ++p) {
        if (p + 2 < NTILE) {
            stage((p + 2) % 3, p + 2);
            asm volatile("s_waitcnt vmcnt(6)" ::: "memory");   // tile p (and p+1) landed
        } else {
            asm volatile("s_waitcnt vmcnt(0)" ::: "memory");
        }
        const char* cp = (const char*)&Bb[0][0] + (p % 3) * (TCOLS * KE * 2);

        auto loadB = [&](s16x8* b, int ni) {
            #pragma unroll
            for (int ks = 0; ks < 6; ++ks)
                b[ks] = *reinterpret_cast<const s16x8*>(
                    cp + (ni * 16 + fr) * ROWB + swb[ks]);
        };
        auto mfmaFold = [&](const s16x8* b) {
            f32x4 acc[4];
            #pragma unroll
            for (int mi = 0; mi < 4; ++mi)
                acc[mi] = __builtin_amdgcn_mfma_f32_16x16x32_bf16(a[0][mi], b[0], zf, 0, 0, 0);
            #pragma unroll
            for (int ks = 1; ks < 6; ++ks)
                #pragma unroll
                for (int mi = 0; mi < 4; ++mi)
                    acc[mi] = __builtin_amdgcn_mfma_f32_16x16x32_bf16(a[ks][mi], b[ks], acc[mi], 0, 0, 0);
            #pragma unroll
            for (int mi = 0; mi < 4; ++mi)
                #pragma unroll
                for (int reg = 0; reg < 4; ++reg) {
                    pv[mi][reg] = fminf(pv[mi][reg], acc[mi][reg]);
                    nv[mi][reg] = fmaxf(nv[mi][reg], acc[mi][reg]);
                }
        };

        s16x8 bX[6], bY[6];
        loadB(bX, 0);
        loadB(bY, 1); mfmaFold(bX);
        loadB(bX, 2); mfmaFold(bY);
        loadB(bY, 3); mfmaFold(bX);
        mfmaFold(bY);

        __builtin_amdgcn_sched_barrier(0);
        __builtin_amdgcn_s_barrier();     // all waves done reading buf p%3
        __builtin_amdgcn_sched_barrier(0);
    }

    // epilogue: reduce across the 16 fr-lanes; fr==0 lanes store this wave's rows
    #pragma unroll
    for (int mi = 0; mi < 4; ++mi)
        #pragma unroll
        for (int reg = 0; reg < 4; ++reg) {
            float p = pv[mi][reg], n = nv[mi][reg];
            #pragma unroll
            for (int off = 1; off < 16; off <<= 1) {
                p = fminf(p, __shfl_xor(p, off, 64));
                n = fmaxf(n, __shfl_xor(n, off, 64));
            }
            if (fr == 0) {
                const int grow = wrow + mi * 16 + fg * 4 + reg;
                pvPart[(size_t)blockIdx.y * NB + grow] = p;
                nvPart[(size_t)blockIdx.y * NB + grow] = n;
            }
        }
}

// ---- kernel 3a: per-row loss, deterministic block partials ----
__global__ void finalize_partial(const float* __restrict__ sqA,
                                 const float* __restrict__ pvPart,
                                 const float* __restrict__ nvPart,
                                 float* __restrict__ fpart) {
    __shared__ float sl[4], sc[4];
    const int tid = threadIdx.x, lane = tid & 63, w = tid >> 6;
    const int i = blockIdx.x * 256 + tid;
    const float PINF = __builtin_inff(), NINF = -__builtin_inff();

    float pMin = PINF, nMax = NINF;
    #pragma unroll
    for (int c = 0; c < NCHUNK; ++c) {
        pMin = fminf(pMin, pvPart[(size_t)c * NB + i]);
        nMax = fmaxf(nMax, nvPart[(size_t)c * NB + i]);
    }
    // positives live at u = d-8 (< -6); negatives at u = d (> -2)
    bool valid = (nMax > -2.0f) && (pMin < -6.0f);
    float dotP = pMin + 8.0f;
    float dotN = nMax;
    float sq = sqA[i];
    float pd = sqrtf(fmaxf(sq + 1.0f - 2.0f * dotP, 0.f) + EPS);
    float nd = sqrtf(fmaxf(sq + 1.0f - 2.0f * dotN, 0.f) + EPS);
    float l  = fmaxf(pd - nd + MARGIN, 0.f);
    float lv = valid ? l : 0.f;
    float cv = valid ? 1.f : 0.f;
    #pragma unroll
    for (int off = 32; off; off >>= 1) {
        lv += __shfl_down(lv, off, 64);
        cv += __shfl_down(cv, off, 64);
    }
    if (lane == 0) { sl[w] = lv; sc[w] = cv; }
    __syncthreads();
    if (tid == 0) {
        fpart[blockIdx.x * 2]     = sl[0] + sl[1] + sl[2] + sl[3];
        fpart[blockIdx.x * 2 + 1] = sc[0] + sc[1] + sc[2] + sc[3];
    }
}

// ---- kernel 3b: final deterministic sum + write ----
__global__ void finalize_write(const float* __restrict__ fpart, float* __restrict__ out) {
    if (threadIdx.x == 0) {
        float L = 0.f, C = 0.f;
        #pragma unroll
        for (int k = 0; k < NB / 256; ++k) { L += fpart[2 * k]; C += fpart[2 * k + 1]; }
        out[0] = (C > 0.f) ? (L / C) : 0.f;
        out[1] = C;
    }
}

extern "C" void kernel_launch(void* const* d_in, const int* in_sizes, int n_in,
                              void* d_out, int out_size, void* d_ws, size_t ws_size,
                              hipStream_t stream) {
    const float* E      = (const float*)d_in[0];
    const int*   labels = (const int*)d_in[1];
    float*       out    = (float*)d_out;

    char* ws = (char*)d_ws;
    size_t off = 0;
    ushort_t* Eb     = (ushort_t*)(ws + off);  off += (size_t)NB * KE * 2;     // 3 MiB
    float*    sqA    = (float*)(ws + off);     off += (size_t)NB * 4;          // 32 KiB
    float*    pvPart = (float*)(ws + off);     off += (size_t)NCHUNK * NB * 4; // 512 KiB
    float*    nvPart = (float*)(ws + off);     off += (size_t)NCHUNK * NB * 4; // 512 KiB
    float*    fpart  = (float*)(ws + off);

    prep_kernel<<<NB / 4, 256, 0, stream>>>(E, labels, Eb, sqA);

    dim3 grid(NB / BMR, NCHUNK);
    triplet_gemm<<<grid, 256, 0, stream>>>(Eb, labels, pvPart, nvPart);

    finalize_partial<<<NB / 256, 256, 0, stream>>>(sqA, pvPart, nvPart, fpart);
    finalize_write<<<1, 64, 0, stream>>>(fpart, out);
}